// Round 1
// baseline (178.830 us; speedup 1.0000x reference)
//
#include <hip/hip_runtime.h>
#include <stdint.h>

typedef unsigned short ushort_t;
typedef __attribute__((ext_vector_type(8))) __bf16 bf16x8;
typedef __attribute__((ext_vector_type(8))) unsigned short ushortx8;
typedef __attribute__((ext_vector_type(4))) float floatx4;

// ---------- helpers ----------
__device__ inline ushort_t f2bf(float f) {
  union { float f; unsigned u; } v; v.f = f;
  unsigned r = v.u + 0x7FFFu + ((v.u >> 16) & 1u);
  return (ushort_t)(r >> 16);
}

__device__ inline floatx4 mfma16(bf16x8 a, bf16x8 b, floatx4 c) {
  return __builtin_amdgcn_mfma_f32_16x16x32_bf16(a, b, c, 0, 0, 0);
}

// async global->LDS, 16B per lane; lds base must be wave-uniform, lane i lands at base + i*16B
__device__ inline void gload_lds16(const ushort_t* g, ushort_t* l) {
  __builtin_amdgcn_global_load_lds((__attribute__((address_space(1))) void*)(void*)(g),
                                   (__attribute__((address_space(3))) void*)(l),
                                   16, 0, 0);
}

// ---------- kernel 1: fp32 -> bf16 cast of x ----------
__global__ __launch_bounds__(256) void k_conv_x(const float* __restrict__ x,
                                                ushort_t* __restrict__ xb) {
  int i = (blockIdx.x * 256 + threadIdx.x) * 4;
  float4 v = *(const float4*)(x + i);
  ushort4 o;
  o.x = f2bf(v.x); o.y = f2bf(v.y); o.z = f2bf(v.z); o.w = f2bf(v.w);
  *(ushort4*)(xb + i) = o;
}

// ---------- kernel 2: W [K,N] fp32 -> Wt [N,K] bf16 (K=512) ----------
__global__ __launch_bounds__(256) void k_conv_wT(const float* __restrict__ src,
                                                 ushort_t* __restrict__ dst, int N) {
  __shared__ float tile[32][33];
  int tid = threadIdx.x;
  int k0 = blockIdx.x * 32, n0 = blockIdx.y * 32;
  int c = tid & 31, r0 = tid >> 5;
#pragma unroll
  for (int i = 0; i < 4; ++i) {
    int r = r0 + i * 8;
    tile[r][c] = src[(size_t)(k0 + r) * N + n0 + c];
  }
  __syncthreads();
#pragma unroll
  for (int i = 0; i < 4; ++i) {
    int r = r0 + i * 8;
    dst[(size_t)(n0 + r) * 512 + k0 + c] = f2bf(tile[c][r]);
  }
}

// ---------- GEMM: C[M,N] = A[M,512] * Bt[N,512]^T  (bf16 in, 128x128 tile) ----------
// EPI=0: scatter to q/k/v [B,H,T,64] bf16.  EPI=1: out fp32 [M,512] + bias.
template <int EPI>
__global__ __launch_bounds__(256)
void k_gemm_bt(const ushort_t* __restrict__ A, const ushort_t* __restrict__ Bt,
               ushort_t* __restrict__ qd, ushort_t* __restrict__ kd, ushort_t* __restrict__ vd,
               float* __restrict__ outf, const float* __restrict__ bias) {
  // lane-ordered frag layout: block blk (16 rows) occupies [blk*512, blk*512+512) shorts,
  // lane l's 8 bf16 (row = blk*16 + (l&15), k = (l>>4)*8..+8) at offset blk*512 + l*8.
  __shared__ __align__(16) ushort_t As[8 * 512];
  __shared__ __align__(16) ushort_t Bs[8 * 512];
  const int tid = threadIdx.x;
  const int w = tid >> 6, l = tid & 63;
  const int lr = l & 15, lq = l >> 4;
  const int m0 = blockIdx.x * 128, n0 = blockIdx.y * 128;
  const int wm = w >> 1, wn = w & 1;

  floatx4 acc[4][4];
#pragma unroll
  for (int i = 0; i < 4; ++i)
#pragma unroll
    for (int j = 0; j < 4; ++j) acc[i][j] = (floatx4)0.0f;

  for (int k0 = 0; k0 < 512; k0 += 32) {
#pragma unroll
    for (int c2 = 0; c2 < 2; ++c2) {
      int blk = w * 2 + c2;
      gload_lds16(A + (size_t)(m0 + blk * 16 + lr) * 512 + k0 + lq * 8, &As[blk * 512]);
      gload_lds16(Bt + (size_t)(n0 + blk * 16 + lr) * 512 + k0 + lq * 8, &Bs[blk * 512]);
    }
    __syncthreads();
    bf16x8 af[4], bfr[4];
#pragma unroll
    for (int i = 0; i < 4; ++i) af[i] = *(const bf16x8*)&As[(wm * 4 + i) * 512 + l * 8];
#pragma unroll
    for (int i = 0; i < 4; ++i) bfr[i] = *(const bf16x8*)&Bs[(wn * 4 + i) * 512 + l * 8];
#pragma unroll
    for (int i = 0; i < 4; ++i)
#pragma unroll
      for (int j = 0; j < 4; ++j) acc[i][j] = mfma16(af[i], bfr[j], acc[i][j]);
    __syncthreads();
  }

#pragma unroll
  for (int i = 0; i < 4; ++i) {
#pragma unroll
    for (int j = 0; j < 4; ++j) {
      int n = n0 + wn * 64 + j * 16 + lr;
      if (EPI == 0) {
        int which = n >> 9, h = (n >> 6) & 7, d = n & 63;
        ushort_t* dst = (which == 0) ? qd : (which == 1) ? kd : vd;
#pragma unroll
        for (int r = 0; r < 4; ++r) {
          int m = m0 + wm * 64 + i * 16 + lq * 4 + r;
          int b = m >> 12, t = m & 4095;
          dst[(((size_t)(b * 8 + h)) * 4096 + t) * 64 + d] = f2bf(acc[i][j][r]);
        }
      } else {
        float bv = bias[n];
#pragma unroll
        for (int r = 0; r < 4; ++r) {
          int m = m0 + wm * 64 + i * 16 + lq * 4 + r;
          outf[(size_t)m * 512 + n] = acc[i][j][r] + bv;
        }
      }
    }
  }
}

// ---------- kernel 4: v [B,H,T,64] -> vt [B,H,64,T] ----------
__global__ __launch_bounds__(256) void k_transpose_v(const ushort_t* __restrict__ v,
                                                     ushort_t* __restrict__ vt) {
  __shared__ __align__(16) ushort_t lt[64][72];
  int tid = threadIdx.x, w = tid >> 6, l = tid & 63;
  int bh = blockIdx.y, t0 = blockIdx.x * 64;
  int row = w * 16 + (l & 15), ch = (l >> 4) * 16;
  const ushort_t* src = v + ((size_t)bh * 4096 + t0 + row) * 64 + ch;
  *(ushortx8*)&lt[row][ch] = *(const ushortx8*)src;
  *(ushortx8*)&lt[row][ch + 8] = *(const ushortx8*)(src + 8);
  __syncthreads();
  ushortx8 o0, o1;
#pragma unroll
  for (int i = 0; i < 8; ++i) o0[i] = lt[w * 16 + i][l];
#pragma unroll
  for (int i = 0; i < 8; ++i) o1[i] = lt[w * 16 + 8 + i][l];
  ushort_t* dst = vt + ((size_t)bh * 64 + l) * 4096 + t0 + w * 16;
  *(ushortx8*)dst = o0;
  *(ushortx8*)(dst + 8) = o1;
}

// ---------- kernel 5: banded attention ----------
// grid (T/64, B*H); block = 4 waves; wave handles 16 query rows, 320-key span.
#define PSTR 328
__global__ __launch_bounds__(256)
void k_attn(const ushort_t* __restrict__ qa, const ushort_t* __restrict__ ka,
            const ushort_t* __restrict__ vta, ushort_t* __restrict__ ao) {
  __shared__ __align__(16) ushort_t P[4 * 16 * PSTR];
  const int tid = threadIdx.x, w = tid >> 6, l = tid & 63;
  const int lr = l & 15, lq = l >> 4;
  const int bh = blockIdx.y, qt0 = blockIdx.x * 64;
  const int qrow = qt0 + w * 16;

  const ushort_t* qp = qa + ((size_t)bh * 4096 + qrow + lr) * 64 + lq * 8;
  bf16x8 qf0 = *(const bf16x8*)qp;
  bf16x8 qf1 = *(const bf16x8*)(qp + 32);

  float sv[20][4];
#pragma unroll
  for (int kt = 0; kt < 20; ++kt) {
    int kb = qt0 - 128 + kt * 16;
    int kc = min(max(kb + lr, 0), 4095);
    const ushort_t* kp = ka + ((size_t)bh * 4096 + kc) * 64 + lq * 8;
    bf16x8 kf0 = *(const bf16x8*)kp;
    bf16x8 kf1 = *(const bf16x8*)(kp + 32);
    floatx4 s = (floatx4)0.0f;
    s = mfma16(qf0, kf0, s);
    s = mfma16(qf1, kf1, s);
#pragma unroll
    for (int r = 0; r < 4; ++r) {
      int qi = qrow + lq * 4 + r;
      int kj = kb + lr;
      int dd = qi - kj;
      bool ok = (kj >= 0) && (kj < 4096) && (dd <= 128) && (dd >= -128);
      sv[kt][r] = ok ? s[r] * 0.125f : -INFINITY;
    }
  }

  float mr[4], inv[4];
#pragma unroll
  for (int r = 0; r < 4; ++r) {
    float m = sv[0][r];
#pragma unroll
    for (int kt = 1; kt < 20; ++kt) m = fmaxf(m, sv[kt][r]);
#pragma unroll
    for (int off = 8; off >= 1; off >>= 1) m = fmaxf(m, __shfl_xor(m, off, 64));
    mr[r] = m;
  }
#pragma unroll
  for (int r = 0; r < 4; ++r) {
    float s = 0.f;
#pragma unroll
    for (int kt = 0; kt < 20; ++kt) {
      float p = exp2f((sv[kt][r] - mr[r]) * 1.4426950408889634f);
      sv[kt][r] = p;
      s += p;
    }
#pragma unroll
    for (int off = 8; off >= 1; off >>= 1) s += __shfl_xor(s, off, 64);
    inv[r] = 1.f / s;
  }

  // normalized P -> LDS in A-operand-friendly [query][key] layout (per-wave region)
  ushort_t* pw = P + w * 16 * PSTR;
#pragma unroll
  for (int kt = 0; kt < 20; ++kt)
#pragma unroll
    for (int r = 0; r < 4; ++r)
      pw[(lq * 4 + r) * PSTR + kt * 16 + lr] = f2bf(sv[kt][r] * inv[r]);
  __syncthreads();

  floatx4 oacc[4];
#pragma unroll
  for (int nt = 0; nt < 4; ++nt) oacc[nt] = (floatx4)0.0f;
  const ushort_t* pr = P + w * 16 * PSTR + lr * PSTR + lq * 8;
#pragma unroll
  for (int kk = 0; kk < 10; ++kk) {
    bf16x8 pf = *(const bf16x8*)(pr + kk * 32);
    int key8 = qt0 - 128 + kk * 32 + lq * 8;
    int kc8 = min(max(key8, 0), 4096 - 8);
#pragma unroll
    for (int nt = 0; nt < 4; ++nt) {
      int d = nt * 16 + lr;
      bf16x8 vf = *(const bf16x8*)(vta + ((size_t)bh * 64 + d) * 4096 + kc8);
      oacc[nt] = mfma16(pf, vf, oacc[nt]);
    }
  }

  int b = bh >> 3, h = bh & 7;
#pragma unroll
  for (int nt = 0; nt < 4; ++nt)
#pragma unroll
    for (int r = 0; r < 4; ++r) {
      int t = qrow + lq * 4 + r;
      int col = h * 64 + nt * 16 + lr;
      ao[((size_t)(b * 4096 + t)) * 512 + col] = f2bf(oacc[nt][r]);
    }
}

// ---------- launch ----------
extern "C" void kernel_launch(void* const* d_in, const int* in_sizes, int n_in,
                              void* d_out, int out_size, void* d_ws, size_t ws_size,
                              hipStream_t stream) {
  const float* x    = (const float*)d_in[0];
  const float* Wqkv = (const float*)d_in[1];
  const float* Wout = (const float*)d_in[2];
  const float* bout = (const float*)d_in[3];
  float* out = (float*)d_out;
  char* ws = (char*)d_ws;
  const size_t MB = 1024 * 1024;

  ushort_t* xb    = (ushort_t*)(ws);                 // 8 MB, dead after gemm1
  ushort_t* wqkvT = (ushort_t*)(ws + 8 * MB);        // 1.5 MB
  ushort_t* woutT = (ushort_t*)(ws + 9 * MB + MB/2); // 0.5 MB
  ushort_t* q     = (ushort_t*)(ws + 10 * MB);       // 8 MB
  ushort_t* k     = (ushort_t*)(ws + 18 * MB);       // 8 MB
  ushort_t* v     = (ushort_t*)(ws + 26 * MB);       // 8 MB
  ushort_t* vt    = (ushort_t*)(ws + 34 * MB);       // 8 MB  (total 42 MB)
  ushort_t* ao    = xb;                              // reuse xb region

  k_conv_x<<<4096, 256, 0, stream>>>(x, xb);
  k_conv_wT<<<dim3(16, 48), 256, 0, stream>>>(Wqkv, wqkvT, 1536);
  k_conv_wT<<<dim3(16, 16), 256, 0, stream>>>(Wout, woutT, 512);
  k_gemm_bt<0><<<dim3(64, 12), 256, 0, stream>>>(xb, wqkvT, q, k, v, nullptr, nullptr);
  k_transpose_v<<<dim3(64, 16), 256, 0, stream>>>(v, vt);
  k_attn<<<dim3(64, 16), 256, 0, stream>>>(q, k, vt, ao);
  k_gemm_bt<1><<<dim3(64, 4), 256, 0, stream>>>(ao, woutT, nullptr, nullptr, nullptr, out, bout);
}

// Round 2
// 158.888 us; speedup vs baseline: 1.1255x; 1.1255x over previous
//
#include <hip/hip_runtime.h>
#include <stdint.h>

typedef unsigned short ushort_t;
typedef __attribute__((ext_vector_type(8))) __bf16 bf16x8;
typedef __attribute__((ext_vector_type(8))) unsigned short ushortx8;
typedef __attribute__((ext_vector_type(4))) float floatx4;
typedef __attribute__((ext_vector_type(4))) unsigned int uint4v;

// ---------- helpers ----------
__device__ inline ushort_t f2bf(float f) {
  union { float f; unsigned u; } v; v.f = f;
  unsigned r = v.u + 0x7FFFu + ((v.u >> 16) & 1u);
  return (ushort_t)(r >> 16);
}

__device__ inline floatx4 mfma16(bf16x8 a, bf16x8 b, floatx4 c) {
  return __builtin_amdgcn_mfma_f32_16x16x32_bf16(a, b, c, 0, 0, 0);
}

// async global->LDS, 16B per lane; lds base wave-uniform, lane i lands at base + i*16B
__device__ inline void gload_lds16(const ushort_t* g, ushort_t* l) {
  __builtin_amdgcn_global_load_lds((__attribute__((address_space(1))) void*)(void*)(g),
                                   (__attribute__((address_space(3))) void*)(l),
                                   16, 0, 0);
}

// ---------- kernel 1: fp32 -> bf16 cast of x ----------
__global__ __launch_bounds__(256) void k_conv_x(const float* __restrict__ x,
                                                ushort_t* __restrict__ xb) {
  int i = (blockIdx.x * 256 + threadIdx.x) * 4;
  float4 v = *(const float4*)(x + i);
  ushort4 o;
  o.x = f2bf(v.x); o.y = f2bf(v.y); o.z = f2bf(v.z); o.w = f2bf(v.w);
  *(ushort4*)(xb + i) = o;
}

// ---------- kernel 2: W [K,N] fp32 -> Wt [N,K] bf16 (K=512) ----------
__global__ __launch_bounds__(256) void k_conv_wT(const float* __restrict__ src,
                                                 ushort_t* __restrict__ dst, int N) {
  __shared__ float tile[32][33];
  int tid = threadIdx.x;
  int k0 = blockIdx.x * 32, n0 = blockIdx.y * 32;
  int c = tid & 31, r0 = tid >> 5;
#pragma unroll
  for (int i = 0; i < 4; ++i) {
    int r = r0 + i * 8;
    tile[r][c] = src[(size_t)(k0 + r) * N + n0 + c];
  }
  __syncthreads();
#pragma unroll
  for (int i = 0; i < 4; ++i) {
    int r = r0 + i * 8;
    dst[(size_t)(n0 + r) * 512 + k0 + c] = f2bf(tile[c][r]);
  }
}

// ---------- GEMM: C[M,N] = A[M,512] * Bt[N,512]^T  (bf16 in, 128x128 tile) ----------
template <int EPI>
__global__ __launch_bounds__(256)
void k_gemm_bt(const ushort_t* __restrict__ A, const ushort_t* __restrict__ Bt,
               ushort_t* __restrict__ qd, ushort_t* __restrict__ kd, ushort_t* __restrict__ vd,
               float* __restrict__ outf, const float* __restrict__ bias) {
  __shared__ __align__(16) ushort_t As[8 * 512];
  __shared__ __align__(16) ushort_t Bs[8 * 512];
  const int tid = threadIdx.x;
  const int w = tid >> 6, l = tid & 63;
  const int lr = l & 15, lq = l >> 4;
  const int m0 = blockIdx.x * 128, n0 = blockIdx.y * 128;
  const int wm = w >> 1, wn = w & 1;

  floatx4 acc[4][4];
#pragma unroll
  for (int i = 0; i < 4; ++i)
#pragma unroll
    for (int j = 0; j < 4; ++j) acc[i][j] = (floatx4)0.0f;

  for (int k0 = 0; k0 < 512; k0 += 32) {
#pragma unroll
    for (int c2 = 0; c2 < 2; ++c2) {
      int blk = w * 2 + c2;
      gload_lds16(A + (size_t)(m0 + blk * 16 + lr) * 512 + k0 + lq * 8, &As[blk * 512]);
      gload_lds16(Bt + (size_t)(n0 + blk * 16 + lr) * 512 + k0 + lq * 8, &Bs[blk * 512]);
    }
    __syncthreads();
    bf16x8 af[4], bfr[4];
#pragma unroll
    for (int i = 0; i < 4; ++i) af[i] = *(const bf16x8*)&As[(wm * 4 + i) * 512 + l * 8];
#pragma unroll
    for (int i = 0; i < 4; ++i) bfr[i] = *(const bf16x8*)&Bs[(wn * 4 + i) * 512 + l * 8];
#pragma unroll
    for (int i = 0; i < 4; ++i)
#pragma unroll
      for (int j = 0; j < 4; ++j) acc[i][j] = mfma16(af[i], bfr[j], acc[i][j]);
    __syncthreads();
  }

#pragma unroll
  for (int i = 0; i < 4; ++i) {
#pragma unroll
    for (int j = 0; j < 4; ++j) {
      int n = n0 + wn * 64 + j * 16 + lr;
      if (EPI == 0) {
        int which = n >> 9, h = (n >> 6) & 7, d = n & 63;
        ushort_t* dst = (which == 0) ? qd : (which == 1) ? kd : vd;
#pragma unroll
        for (int r = 0; r < 4; ++r) {
          int m = m0 + wm * 64 + i * 16 + lq * 4 + r;
          int b = m >> 12, t = m & 4095;
          dst[(((size_t)(b * 8 + h)) * 4096 + t) * 64 + d] = f2bf(acc[i][j][r]);
        }
      } else {
        float bv = bias[n];
#pragma unroll
        for (int r = 0; r < 4; ++r) {
          int m = m0 + wm * 64 + i * 16 + lq * 4 + r;
          outf[(size_t)m * 512 + n] = acc[i][j][r] + bv;
        }
      }
    }
  }
}

// ---------- kernel 4: v [B,H,T,64] -> vt [B,H,64,T] ----------
__global__ __launch_bounds__(256) void k_transpose_v(const ushort_t* __restrict__ v,
                                                     ushort_t* __restrict__ vt) {
  __shared__ __align__(16) ushort_t lt[64][72];
  int tid = threadIdx.x, w = tid >> 6, l = tid & 63;
  int bh = blockIdx.y, t0 = blockIdx.x * 64;
  int row = w * 16 + (l & 15), ch = (l >> 4) * 16;
  const ushort_t* src = v + ((size_t)bh * 4096 + t0 + row) * 64 + ch;
  *(ushortx8*)&lt[row][ch] = *(const ushortx8*)src;
  *(ushortx8*)&lt[row][ch + 8] = *(const ushortx8*)(src + 8);
  __syncthreads();
  ushortx8 o0, o1;
#pragma unroll
  for (int i = 0; i < 8; ++i) o0[i] = lt[w * 16 + i][l];
#pragma unroll
  for (int i = 0; i < 8; ++i) o1[i] = lt[w * 16 + 8 + i][l];
  ushort_t* dst = vt + ((size_t)bh * 64 + l) * 4096 + t0 + w * 16;
  *(ushortx8*)dst = o0;
  *(ushortx8*)(dst + 8) = o1;
}

// ---------- kernel 5: banded attention (latency-restructured) ----------
// grid (T/64, B*H); 4 waves/block; wave owns 16 queries (q = qrow + lr).
// S^T layout from mfma(a=K, b=Q): lane holds keys kt*16+lq*4+{0..3} for query lr.
// No max-subtract (logits ~N(0,1)); exp+pack fused into QK loop; unnormalized P in
// registers (bf16-packed); C->A layout transform via shfl; V staged in LDS async.
__global__ __launch_bounds__(256)
void k_attn(const ushort_t* __restrict__ qa, const ushort_t* __restrict__ ka,
            const ushort_t* __restrict__ vta, ushort_t* __restrict__ ao) {
  __shared__ __align__(16) ushort_t Vs[40 * 512];  // 40960 B: 4 blocks/CU
  const int tid = threadIdx.x, w = tid >> 6, l = tid & 63;
  const int lr = l & 15, lq = l >> 4;
  const int bh = blockIdx.y, qt0 = blockIdx.x * 64;
  const int qrow = qt0 + w * 16;

  // --- issue async V staging first (tiles t = kt2*4+nt; wave w stages t in [w*10, w*10+10)) ---
  const ushort_t* vbase = vta + (size_t)bh * 64 * 4096;
#pragma unroll
  for (int i = 0; i < 10; ++i) {
    int t = w * 10 + i;
    int kt2 = t >> 2, nt = t & 3;
    int d = nt * 16 + lr;
    int key = qt0 - 128 + kt2 * 32 + lq * 8;
    key = min(max(key, 0), 4088);
    gload_lds16(vbase + (size_t)d * 4096 + key, &Vs[t * 512]);
  }

  // --- Q frags (B operand: n=q=lr, k=ch) ---
  const ushort_t* qp = qa + ((size_t)bh * 4096 + qrow + lr) * 64 + lq * 8;
  bf16x8 qf0 = *(const bf16x8*)qp;
  bf16x8 qf1 = *(const bf16x8*)(qp + 32);

  // --- QK + fused exp/pack.  17 tiles cover rel keys [0,272) (base qrow-128). ---
  const float C = 0.125f * 1.4426950408889634f;
  uint2 pk[18];
  pk[17].x = 0u; pk[17].y = 0u;
  float ps = 0.f;
#pragma unroll
  for (int kt = 0; kt < 17; ++kt) {
    int kb = qrow - 128 + kt * 16;
    int kc = min(max(kb + lr, 0), 4095);
    const ushort_t* kp = ka + ((size_t)bh * 4096 + kc) * 64 + lq * 8;
    bf16x8 kf0 = *(const bf16x8*)kp;
    bf16x8 kf1 = *(const bf16x8*)(kp + 32);
    floatx4 s = (floatx4)0.0f;
    s = mfma16(kf0, qf0, s);
    s = mfma16(kf1, qf1, s);
    float p[4];
#pragma unroll
    for (int r = 0; r < 4; ++r) {
      int r_rel = kt * 16 + lq * 4 + r;      // key rel index (lane-varying via lq)
      int kj = qrow - 128 + r_rel;           // absolute key
      bool ok = (kj >= 0) && (kj < 4096) && (r_rel >= lr) && (r_rel - lr <= 256);
      float e = ok ? exp2f(s[r] * C) : 0.f;
      ps += e;
      p[r] = e;
    }
    pk[kt].x = (unsigned)f2bf(p[0]) | ((unsigned)f2bf(p[1]) << 16);
    pk[kt].y = (unsigned)f2bf(p[2]) | ((unsigned)f2bf(p[3]) << 16);
  }

  // --- row-sum across the 4 lq lanes of each query ---
  ps += __shfl_xor(ps, 16, 64);
  ps += __shfl_xor(ps, 32, 64);
  float inv = __builtin_amdgcn_rcpf(ps);

  __syncthreads();  // V staging complete (single barrier)

  // --- PV: transform P (C-layout) -> A-frag via shfl; V frags from LDS ---
  floatx4 oacc[4];
#pragma unroll
  for (int nt = 0; nt < 4; ++nt) oacc[nt] = (floatx4)0.0f;
  const int srcA = ((l >> 4) & 1) * 32 + lr;   // provider of j0..3
  const int srcB = srcA + 16;                  // provider of j4..7
  const bool selhi = (l & 32) != 0;            // kt = 2kk + (lq'>>1)

#pragma unroll
  for (int kk = 0; kk < 9; ++kk) {
    unsigned e0 = __shfl(pk[2 * kk].x, srcA, 64);
    unsigned e1 = __shfl(pk[2 * kk].y, srcA, 64);
    unsigned e2 = __shfl(pk[2 * kk].x, srcB, 64);
    unsigned e3 = __shfl(pk[2 * kk].y, srcB, 64);
    unsigned o0 = __shfl(pk[2 * kk + 1].x, srcA, 64);
    unsigned o1 = __shfl(pk[2 * kk + 1].y, srcA, 64);
    unsigned o2 = __shfl(pk[2 * kk + 1].x, srcB, 64);
    unsigned o3 = __shfl(pk[2 * kk + 1].y, srcB, 64);
    union { uint4v u; bf16x8 b; } pu;
    pu.u[0] = selhi ? o0 : e0;
    pu.u[1] = selhi ? o1 : e1;
    pu.u[2] = selhi ? o2 : e2;
    pu.u[3] = selhi ? o3 : e3;

    int keyrel = w * 16 + kk * 32 + lq * 8;    // block-relative key of this frag chunk
    keyrel = min(keyrel, 312);                 // clamp: only P==0 region affected
    int kt2 = keyrel >> 5, seg = (keyrel >> 3) & 3;
    const ushort_t* vsp = &Vs[kt2 * 2048 + seg * 128 + lr * 8];
#pragma unroll
    for (int nt = 0; nt < 4; ++nt) {
      bf16x8 vf = *(const bf16x8*)(vsp + nt * 512);
      oacc[nt] = mfma16(pu.b, vf, oacc[nt]);
    }
  }

  // --- epilogue: normalize by 1/sum (redistribute inv to row q=lq*4+r), store ---
  float invr[4];
#pragma unroll
  for (int r = 0; r < 4; ++r) invr[r] = __shfl(inv, lq * 4 + r, 64);

  int b = bh >> 3, h = bh & 7;
#pragma unroll
  for (int nt = 0; nt < 4; ++nt)
#pragma unroll
    for (int r = 0; r < 4; ++r) {
      int t = qrow + lq * 4 + r;
      int col = h * 64 + nt * 16 + lr;
      ao[((size_t)(b * 4096 + t)) * 512 + col] = f2bf(oacc[nt][r] * invr[r]);
    }
}

// ---------- launch ----------
extern "C" void kernel_launch(void* const* d_in, const int* in_sizes, int n_in,
                              void* d_out, int out_size, void* d_ws, size_t ws_size,
                              hipStream_t stream) {
  const float* x    = (const float*)d_in[0];
  const float* Wqkv = (const float*)d_in[1];
  const float* Wout = (const float*)d_in[2];
  const float* bout = (const float*)d_in[3];
  float* out = (float*)d_out;
  char* ws = (char*)d_ws;
  const size_t MB = 1024 * 1024;

  ushort_t* xb    = (ushort_t*)(ws);                 // 8 MB, dead after gemm1
  ushort_t* wqkvT = (ushort_t*)(ws + 8 * MB);        // 1.5 MB
  ushort_t* woutT = (ushort_t*)(ws + 9 * MB + MB/2); // 0.5 MB
  ushort_t* q     = (ushort_t*)(ws + 10 * MB);       // 8 MB
  ushort_t* k     = (ushort_t*)(ws + 18 * MB);       // 8 MB
  ushort_t* v     = (ushort_t*)(ws + 26 * MB);       // 8 MB
  ushort_t* vt    = (ushort_t*)(ws + 34 * MB);       // 8 MB  (total 42 MB)
  ushort_t* ao    = xb;                              // reuse xb region

  k_conv_x<<<4096, 256, 0, stream>>>(x, xb);
  k_conv_wT<<<dim3(16, 48), 256, 0, stream>>>(Wqkv, wqkvT, 1536);
  k_conv_wT<<<dim3(16, 16), 256, 0, stream>>>(Wout, woutT, 512);
  k_gemm_bt<0><<<dim3(64, 12), 256, 0, stream>>>(xb, wqkvT, q, k, v, nullptr, nullptr);
  k_transpose_v<<<dim3(64, 16), 256, 0, stream>>>(v, vt);
  k_attn<<<dim3(64, 16), 256, 0, stream>>>(q, k, vt, ao);
  k_gemm_bt<1><<<dim3(64, 4), 256, 0, stream>>>(ao, woutT, nullptr, nullptr, nullptr, out, bout);
}

// Round 3
// 156.700 us; speedup vs baseline: 1.1412x; 1.0140x over previous
//
#include <hip/hip_runtime.h>
#include <stdint.h>

typedef unsigned short ushort_t;
typedef __attribute__((ext_vector_type(8))) __bf16 bf16x8;
typedef __attribute__((ext_vector_type(8))) unsigned short ushortx8;
typedef __attribute__((ext_vector_type(4))) float floatx4;
typedef __attribute__((ext_vector_type(4))) unsigned int uint4v;

// ---------- helpers ----------
__device__ inline ushort_t f2bf(float f) {
  union { float f; unsigned u; } v; v.f = f;
  unsigned r = v.u + 0x7FFFu + ((v.u >> 16) & 1u);
  return (ushort_t)(r >> 16);
}

__device__ inline floatx4 mfma16(bf16x8 a, bf16x8 b, floatx4 c) {
  return __builtin_amdgcn_mfma_f32_16x16x32_bf16(a, b, c, 0, 0, 0);
}

// async global->LDS, 16B per lane; lds base wave-uniform, lane i lands at base + i*16B
__device__ inline void gload_lds16(const ushort_t* g, ushort_t* l) {
  __builtin_amdgcn_global_load_lds((__attribute__((address_space(1))) void*)(void*)(g),
                                   (__attribute__((address_space(3))) void*)(l),
                                   16, 0, 0);
}

// ---------- kernel 1: fused prep — x cast + both W transposes ----------
// grid: [0,4096) x-cast; [4096,4864) Wqkv^T (16x48 tiles); [4864,5120) Wout^T (16x16)
__global__ __launch_bounds__(256)
void k_prep(const float* __restrict__ x, ushort_t* __restrict__ xb,
            const float* __restrict__ Wqkv, ushort_t* __restrict__ wqkvT,
            const float* __restrict__ Wout, ushort_t* __restrict__ woutT) {
  int bx = blockIdx.x, tid = threadIdx.x;
  if (bx < 4096) {
    int i = (bx * 256 + tid) * 4;
    float4 v = *(const float4*)(x + i);
    ushort4 o;
    o.x = f2bf(v.x); o.y = f2bf(v.y); o.z = f2bf(v.z); o.w = f2bf(v.w);
    *(ushort4*)(xb + i) = o;
    return;
  }
  __shared__ float tile[32][33];
  const float* src; ushort_t* dst; int N, id;
  if (bx < 4096 + 768) { id = bx - 4096; src = Wqkv; dst = wqkvT; N = 1536; }
  else                 { id = bx - 4864; src = Wout; dst = woutT; N = 512;  }
  int k0 = (id & 15) * 32, n0 = (id >> 4) * 32;
  int c = tid & 31, r0 = tid >> 5;
#pragma unroll
  for (int i = 0; i < 4; ++i) {
    int r = r0 + i * 8;
    tile[r][c] = src[(size_t)(k0 + r) * N + n0 + c];
  }
  __syncthreads();
#pragma unroll
  for (int i = 0; i < 4; ++i) {
    int r = r0 + i * 8;
    dst[(size_t)(n0 + r) * 512 + k0 + c] = f2bf(tile[c][r]);
  }
}

// ---------- GEMM: C[M,N] = A[M,512] * Bt[N,512]^T, BK=64, MT x 128 tile ----------
// EPI=0: scatter to q/k/v [B,H,T,64] bf16.  EPI=1: out fp32 [M,512] + bias.
template <int EPI, int MT>
__global__ __launch_bounds__(256)
void k_gemm_bt(const ushort_t* __restrict__ A, const ushort_t* __restrict__ Bt,
               ushort_t* __restrict__ qd, ushort_t* __restrict__ kd, ushort_t* __restrict__ vd,
               float* __restrict__ outf, const float* __restrict__ bias) {
  constexpr int ABLK = MT / 16;        // 16-row blocks of A
  constexpr int AISS = ABLK * 2;       // staging issues for A (2 per block, k-halves)
  constexpr int TOT  = AISS + 16;      // + B: 8 blocks * 2 halves
  constexpr int PER  = TOT / 4;        // issues per wave
  constexpr int IT   = MT / 32;        // i-subtiles per wave
  __shared__ __align__(16) ushort_t As[ABLK * 1024];
  __shared__ __align__(16) ushort_t Bs[8 * 1024];
  const int tid = threadIdx.x;
  const int w = tid >> 6, l = tid & 63;
  const int lr = l & 15, lq = l >> 4;
  const int m0 = blockIdx.x * MT, n0 = blockIdx.y * 128;
  const int wm = w >> 1, wn = w & 1;

  floatx4 acc[IT][4];
#pragma unroll
  for (int i = 0; i < IT; ++i)
#pragma unroll
    for (int j = 0; j < 4; ++j) acc[i][j] = (floatx4)0.0f;

  for (int k0 = 0; k0 < 512; k0 += 64) {
#pragma unroll
    for (int i = 0; i < PER; ++i) {
      int idx = w * PER + i;
      if (idx < AISS) {
        int blk = idx >> 1, half = idx & 1;
        gload_lds16(A + (size_t)(m0 + blk * 16 + lr) * 512 + k0 + half * 32 + lq * 8,
                    &As[blk * 1024 + half * 512]);
      } else {
        int j = idx - AISS, blk = j >> 1, half = j & 1;
        gload_lds16(Bt + (size_t)(n0 + blk * 16 + lr) * 512 + k0 + half * 32 + lq * 8,
                    &Bs[blk * 1024 + half * 512]);
      }
    }
    __syncthreads();
#pragma unroll
    for (int half = 0; half < 2; ++half) {
      bf16x8 af[IT], bfr[4];
#pragma unroll
      for (int i = 0; i < IT; ++i)
        af[i] = *(const bf16x8*)&As[(wm * IT + i) * 1024 + half * 512 + l * 8];
#pragma unroll
      for (int j = 0; j < 4; ++j)
        bfr[j] = *(const bf16x8*)&Bs[(wn * 4 + j) * 1024 + half * 512 + l * 8];
#pragma unroll
      for (int i = 0; i < IT; ++i)
#pragma unroll
        for (int j = 0; j < 4; ++j) acc[i][j] = mfma16(af[i], bfr[j], acc[i][j]);
    }
    __syncthreads();
  }

#pragma unroll
  for (int i = 0; i < IT; ++i) {
#pragma unroll
    for (int j = 0; j < 4; ++j) {
      int n = n0 + wn * 64 + j * 16 + lr;
      if (EPI == 0) {
        int which = n >> 9, h = (n >> 6) & 7, d = n & 63;
        ushort_t* dst = (which == 0) ? qd : (which == 1) ? kd : vd;
#pragma unroll
        for (int r = 0; r < 4; ++r) {
          int m = m0 + wm * (IT * 16) + i * 16 + lq * 4 + r;
          int b = m >> 12, t = m & 4095;
          dst[(((size_t)(b * 8 + h)) * 4096 + t) * 64 + d] = f2bf(acc[i][j][r]);
        }
      } else {
        float bv = bias[n];
#pragma unroll
        for (int r = 0; r < 4; ++r) {
          int m = m0 + wm * (IT * 16) + i * 16 + lq * 4 + r;
          outf[(size_t)m * 512 + n] = acc[i][j][r] + bv;
        }
      }
    }
  }
}

// ---------- kernel 3: v [B,H,T,64] -> vt [B,H,64,T] ----------
__global__ __launch_bounds__(256) void k_transpose_v(const ushort_t* __restrict__ v,
                                                     ushort_t* __restrict__ vt) {
  __shared__ __align__(16) ushort_t lt[64][72];
  int tid = threadIdx.x, w = tid >> 6, l = tid & 63;
  int bh = blockIdx.y, t0 = blockIdx.x * 64;
  int row = w * 16 + (l & 15), ch = (l >> 4) * 16;
  const ushort_t* src = v + ((size_t)bh * 4096 + t0 + row) * 64 + ch;
  *(ushortx8*)&lt[row][ch] = *(const ushortx8*)src;
  *(ushortx8*)&lt[row][ch + 8] = *(const ushortx8*)(src + 8);
  __syncthreads();
  ushortx8 o0, o1;
#pragma unroll
  for (int i = 0; i < 8; ++i) o0[i] = lt[w * 16 + i][l];
#pragma unroll
  for (int i = 0; i < 8; ++i) o1[i] = lt[w * 16 + 8 + i][l];
  ushort_t* dst = vt + ((size_t)bh * 64 + l) * 4096 + t0 + w * 16;
  *(ushortx8*)dst = o0;
  *(ushortx8*)(dst + 8) = o1;
}

// ---------- kernel 4: banded attention ----------
__global__ __launch_bounds__(256)
void k_attn(const ushort_t* __restrict__ qa, const ushort_t* __restrict__ ka,
            const ushort_t* __restrict__ vta, ushort_t* __restrict__ ao) {
  __shared__ __align__(16) ushort_t Vs[40 * 512];  // 40960 B
  const int tid = threadIdx.x, w = tid >> 6, l = tid & 63;
  const int lr = l & 15, lq = l >> 4;
  const int bh = blockIdx.y, qt0 = blockIdx.x * 64;
  const int qrow = qt0 + w * 16;

  // async V staging first (tiles t = kt2*4+nt; wave w stages t in [w*10, w*10+10))
  const ushort_t* vbase = vta + (size_t)bh * 64 * 4096;
#pragma unroll
  for (int i = 0; i < 10; ++i) {
    int t = w * 10 + i;
    int kt2 = t >> 2, nt = t & 3;
    int d = nt * 16 + lr;
    int key = qt0 - 128 + kt2 * 32 + lq * 8;
    key = min(max(key, 0), 4088);
    gload_lds16(vbase + (size_t)d * 4096 + key, &Vs[t * 512]);
  }

  const ushort_t* qp = qa + ((size_t)bh * 4096 + qrow + lr) * 64 + lq * 8;
  bf16x8 qf0 = *(const bf16x8*)qp;
  bf16x8 qf1 = *(const bf16x8*)(qp + 32);

  const float C = 0.125f * 1.4426950408889634f;
  uint2 pk[18];
  pk[17].x = 0u; pk[17].y = 0u;
  float ps = 0.f;
#pragma unroll
  for (int kt = 0; kt < 17; ++kt) {
    int kb = qrow - 128 + kt * 16;
    int kc = min(max(kb + lr, 0), 4095);
    const ushort_t* kp = ka + ((size_t)bh * 4096 + kc) * 64 + lq * 8;
    bf16x8 kf0 = *(const bf16x8*)kp;
    bf16x8 kf1 = *(const bf16x8*)(kp + 32);
    floatx4 s = (floatx4)0.0f;
    s = mfma16(kf0, qf0, s);
    s = mfma16(kf1, qf1, s);
    float p[4];
#pragma unroll
    for (int r = 0; r < 4; ++r) {
      int r_rel = kt * 16 + lq * 4 + r;
      int kj = qrow - 128 + r_rel;
      bool ok = (kj >= 0) && (kj < 4096) && (r_rel >= lr) && (r_rel - lr <= 256);
      float e = ok ? exp2f(s[r] * C) : 0.f;
      ps += e;
      p[r] = e;
    }
    pk[kt].x = (unsigned)f2bf(p[0]) | ((unsigned)f2bf(p[1]) << 16);
    pk[kt].y = (unsigned)f2bf(p[2]) | ((unsigned)f2bf(p[3]) << 16);
  }

  ps += __shfl_xor(ps, 16, 64);
  ps += __shfl_xor(ps, 32, 64);
  float inv = __builtin_amdgcn_rcpf(ps);

  __syncthreads();  // V staging complete

  floatx4 oacc[4];
#pragma unroll
  for (int nt = 0; nt < 4; ++nt) oacc[nt] = (floatx4)0.0f;
  const int srcA = ((l >> 4) & 1) * 32 + lr;
  const int srcB = srcA + 16;
  const bool selhi = (l & 32) != 0;

#pragma unroll
  for (int kk = 0; kk < 9; ++kk) {
    unsigned e0 = __shfl(pk[2 * kk].x, srcA, 64);
    unsigned e1 = __shfl(pk[2 * kk].y, srcA, 64);
    unsigned e2 = __shfl(pk[2 * kk].x, srcB, 64);
    unsigned e3 = __shfl(pk[2 * kk].y, srcB, 64);
    unsigned o0 = __shfl(pk[2 * kk + 1].x, srcA, 64);
    unsigned o1 = __shfl(pk[2 * kk + 1].y, srcA, 64);
    unsigned o2 = __shfl(pk[2 * kk + 1].x, srcB, 64);
    unsigned o3 = __shfl(pk[2 * kk + 1].y, srcB, 64);
    union { uint4v u; bf16x8 b; } pu;
    pu.u[0] = selhi ? o0 : e0;
    pu.u[1] = selhi ? o1 : e1;
    pu.u[2] = selhi ? o2 : e2;
    pu.u[3] = selhi ? o3 : e3;

    int keyrel = w * 16 + kk * 32 + lq * 8;
    keyrel = min(keyrel, 312);
    int kt2 = keyrel >> 5, seg = (keyrel >> 3) & 3;
    const ushort_t* vsp = &Vs[kt2 * 2048 + seg * 128 + lr * 8];
#pragma unroll
    for (int nt = 0; nt < 4; ++nt) {
      bf16x8 vf = *(const bf16x8*)(vsp + nt * 512);
      oacc[nt] = mfma16(pu.b, vf, oacc[nt]);
    }
  }

  float invr[4];
#pragma unroll
  for (int r = 0; r < 4; ++r) invr[r] = __shfl(inv, lq * 4 + r, 64);

  int b = bh >> 3, h = bh & 7;
#pragma unroll
  for (int nt = 0; nt < 4; ++nt)
#pragma unroll
    for (int r = 0; r < 4; ++r) {
      int t = qrow + lq * 4 + r;
      int col = h * 64 + nt * 16 + lr;
      ao[((size_t)(b * 4096 + t)) * 512 + col] = f2bf(oacc[nt][r] * invr[r]);
    }
}

// ---------- launch ----------
extern "C" void kernel_launch(void* const* d_in, const int* in_sizes, int n_in,
                              void* d_out, int out_size, void* d_ws, size_t ws_size,
                              hipStream_t stream) {
  const float* x    = (const float*)d_in[0];
  const float* Wqkv = (const float*)d_in[1];
  const float* Wout = (const float*)d_in[2];
  const float* bout = (const float*)d_in[3];
  float* out = (float*)d_out;
  char* ws = (char*)d_ws;
  const size_t MB = 1024 * 1024;

  ushort_t* xb    = (ushort_t*)(ws);                 // 8 MB, dead after gemm1
  ushort_t* wqkvT = (ushort_t*)(ws + 8 * MB);        // 1.5 MB
  ushort_t* woutT = (ushort_t*)(ws + 9 * MB + MB/2); // 0.5 MB
  ushort_t* q     = (ushort_t*)(ws + 10 * MB);       // 8 MB
  ushort_t* k     = (ushort_t*)(ws + 18 * MB);       // 8 MB
  ushort_t* v     = (ushort_t*)(ws + 26 * MB);       // 8 MB
  ushort_t* vt    = (ushort_t*)(ws + 34 * MB);       // 8 MB  (total 42 MB)
  ushort_t* ao    = xb;                              // reuse xb region

  k_prep<<<5120, 256, 0, stream>>>(x, xb, Wqkv, wqkvT, Wout, woutT);
  k_gemm_bt<0, 128><<<dim3(64, 12), 256, 0, stream>>>(xb, wqkvT, q, k, v, nullptr, nullptr);
  k_transpose_v<<<dim3(64, 16), 256, 0, stream>>>(v, vt);
  k_attn<<<dim3(64, 16), 256, 0, stream>>>(q, k, vt, ao);
  k_gemm_bt<1, 64><<<dim3(128, 4), 256, 0, stream>>>(ao, woutT, nullptr, nullptr, nullptr, out, bout);
}

// Round 4
// 143.808 us; speedup vs baseline: 1.2435x; 1.0896x over previous
//
#include <hip/hip_runtime.h>
#include <stdint.h>

typedef unsigned short ushort_t;
typedef __attribute__((ext_vector_type(8))) __bf16 bf16x8;
typedef __attribute__((ext_vector_type(8))) unsigned short ushortx8;
typedef __attribute__((ext_vector_type(4))) float floatx4;
typedef __attribute__((ext_vector_type(4))) unsigned int uint4v;

// ---------- helpers ----------
__device__ inline ushort_t f2bf(float f) {
  union { float f; unsigned u; } v; v.f = f;
  unsigned r = v.u + 0x7FFFu + ((v.u >> 16) & 1u);
  return (ushort_t)(r >> 16);
}

__device__ inline floatx4 mfma16(bf16x8 a, bf16x8 b, floatx4 c) {
  return __builtin_amdgcn_mfma_f32_16x16x32_bf16(a, b, c, 0, 0, 0);
}

__device__ inline void gload_lds16(const ushort_t* g, ushort_t* l) {
  __builtin_amdgcn_global_load_lds((__attribute__((address_space(1))) void*)(void*)(g),
                                   (__attribute__((address_space(3))) void*)(l),
                                   16, 0, 0);
}

// ---------- kernel 1: fused prep — x cast + both W transposes ----------
__global__ __launch_bounds__(256)
void k_prep(const float* __restrict__ x, ushort_t* __restrict__ xb,
            const float* __restrict__ Wqkv, ushort_t* __restrict__ wqkvT,
            const float* __restrict__ Wout, ushort_t* __restrict__ woutT) {
  int bx = blockIdx.x, tid = threadIdx.x;
  if (bx < 4096) {
    int i = (bx * 256 + tid) * 4;
    float4 v = *(const float4*)(x + i);
    ushort4 o;
    o.x = f2bf(v.x); o.y = f2bf(v.y); o.z = f2bf(v.z); o.w = f2bf(v.w);
    *(ushort4*)(xb + i) = o;
    return;
  }
  __shared__ float tile[32][33];
  const float* src; ushort_t* dst; int N, id;
  if (bx < 4096 + 768) { id = bx - 4096; src = Wqkv; dst = wqkvT; N = 1536; }
  else                 { id = bx - 4864; src = Wout; dst = woutT; N = 512;  }
  int k0 = (id & 15) * 32, n0 = (id >> 4) * 32;
  int c = tid & 31, r0 = tid >> 5;
#pragma unroll
  for (int i = 0; i < 4; ++i) {
    int r = r0 + i * 8;
    tile[r][c] = src[(size_t)(k0 + r) * N + n0 + c];
  }
  __syncthreads();
#pragma unroll
  for (int i = 0; i < 4; ++i) {
    int r = r0 + i * 8;
    dst[(size_t)(n0 + r) * 512 + k0 + c] = f2bf(tile[c][r]);
  }
}

// ---------- GEMM1: qkv = xb @ wqkvT^T, 128x128 tile, BK=64 ----------
// Epilogue through LDS C-tile: q/k -> [b,h,t,64] coalesced 16B; v -> vt[b,h,64,t] coalesced 16B.
__global__ __launch_bounds__(256)
void k_gemm1(const ushort_t* __restrict__ A, const ushort_t* __restrict__ Bt,
             ushort_t* __restrict__ qd, ushort_t* __restrict__ kd,
             ushort_t* __restrict__ vtd) {
  __shared__ __align__(16) ushort_t smem[17408];   // staging 32KB, then C-tile 128x136
  ushort_t* As = smem;           // 8192 shorts
  ushort_t* Bs = smem + 8192;    // 8192 shorts
  const int tid = threadIdx.x;
  const int w = tid >> 6, l = tid & 63;
  const int lr = l & 15, lq = l >> 4;
  const int m0 = blockIdx.x * 128, n0 = blockIdx.y * 128;
  const int wm = w >> 1, wn = w & 1;

  floatx4 acc[4][4];
#pragma unroll
  for (int i = 0; i < 4; ++i)
#pragma unroll
    for (int j = 0; j < 4; ++j) acc[i][j] = (floatx4)0.0f;

  for (int k0 = 0; k0 < 512; k0 += 64) {
#pragma unroll
    for (int i = 0; i < 8; ++i) {
      int idx = w * 8 + i;
      if (idx < 16) {
        int blk = idx >> 1, half = idx & 1;
        gload_lds16(A + (size_t)(m0 + blk * 16 + lr) * 512 + k0 + half * 32 + lq * 8,
                    &As[blk * 1024 + half * 512]);
      } else {
        int j = idx - 16, blk = j >> 1, half = j & 1;
        gload_lds16(Bt + (size_t)(n0 + blk * 16 + lr) * 512 + k0 + half * 32 + lq * 8,
                    &Bs[blk * 1024 + half * 512]);
      }
    }
    __syncthreads();
#pragma unroll
    for (int half = 0; half < 2; ++half) {
      bf16x8 af[4], bfr[4];
#pragma unroll
      for (int i = 0; i < 4; ++i)
        af[i] = *(const bf16x8*)&As[(wm * 4 + i) * 1024 + half * 512 + l * 8];
#pragma unroll
      for (int j = 0; j < 4; ++j)
        bfr[j] = *(const bf16x8*)&Bs[(wn * 4 + j) * 1024 + half * 512 + l * 8];
#pragma unroll
      for (int i = 0; i < 4; ++i)
#pragma unroll
        for (int j = 0; j < 4; ++j) acc[i][j] = mfma16(af[i], bfr[j], acc[i][j]);
    }
    __syncthreads();
  }

  if (blockIdx.y < 8) {
    // q/k: C-tile [t_rel][n_rel], stride 136
#pragma unroll
    for (int i = 0; i < 4; ++i)
#pragma unroll
      for (int j = 0; j < 4; ++j) {
        int col = wn * 64 + j * 16 + lr;
#pragma unroll
        for (int r = 0; r < 4; ++r) {
          int row = wm * 64 + i * 16 + lq * 4 + r;
          smem[row * 136 + col] = f2bf(acc[i][j][r]);
        }
      }
    __syncthreads();
#pragma unroll
    for (int p = 0; p < 8; ++p) {
      int row = p * 16 + (tid >> 4), c8 = (tid & 15) * 8;
      ushortx8 vv = *(const ushortx8*)&smem[row * 136 + c8];
      int n = n0 + c8;
      ushort_t* dst = (n >> 9) ? kd : qd;
      int h = (n >> 6) & 7, d = n & 63;
      int m = m0 + row, b = m >> 12, t = m & 4095;
      *(ushortx8*)&dst[(((size_t)(b * 8 + h)) * 4096 + t) * 64 + d] = vv;
    }
  } else {
    // v: transposed C-tile [n_rel(d)][t_rel], stride 136, packed b64 writes
#pragma unroll
    for (int i = 0; i < 4; ++i)
#pragma unroll
      for (int j = 0; j < 4; ++j) {
        int dcol = wn * 64 + j * 16 + lr;
        int trow = wm * 64 + i * 16 + lq * 4;
        ushort4 pv;
        pv.x = f2bf(acc[i][j][0]); pv.y = f2bf(acc[i][j][1]);
        pv.z = f2bf(acc[i][j][2]); pv.w = f2bf(acc[i][j][3]);
        *(ushort4*)&smem[dcol * 136 + trow] = pv;
      }
    __syncthreads();
#pragma unroll
    for (int p = 0; p < 8; ++p) {
      int row = p * 16 + (tid >> 4), c8 = (tid & 15) * 8;  // row = n_rel, c8 = t_rel
      ushortx8 vv = *(const ushortx8*)&smem[row * 136 + c8];
      int n = n0 + row, h = (n >> 6) & 7, d = n & 63;
      int m = m0 + c8, b = m >> 12, t = m & 4095;
      *(ushortx8*)&vtd[(((size_t)(b * 8 + h)) * 64 + d) * 4096 + t] = vv;
    }
  }
}

// ---------- GEMM2: out = ao @ woutT^T + bias, 64x128 tile, fp32 out ----------
__global__ __launch_bounds__(256)
void k_gemm2(const ushort_t* __restrict__ A, const ushort_t* __restrict__ Bt,
             float* __restrict__ outf, const float* __restrict__ bias) {
  __shared__ __align__(16) char smemc[33792];  // staging 24KB, then C-tile 64x132 fp32
  ushort_t* As = (ushort_t*)smemc;             // 4096 shorts
  ushort_t* Bs = (ushort_t*)(smemc + 8192);    // 8192 shorts
  float* Cs = (float*)smemc;
  const int tid = threadIdx.x;
  const int w = tid >> 6, l = tid & 63;
  const int lr = l & 15, lq = l >> 4;
  const int m0 = blockIdx.x * 64, n0 = blockIdx.y * 128;
  const int wm = w >> 1, wn = w & 1;

  floatx4 acc[2][4];
#pragma unroll
  for (int i = 0; i < 2; ++i)
#pragma unroll
    for (int j = 0; j < 4; ++j) acc[i][j] = (floatx4)0.0f;

  for (int k0 = 0; k0 < 512; k0 += 64) {
#pragma unroll
    for (int i = 0; i < 6; ++i) {
      int idx = w * 6 + i;
      if (idx < 8) {
        int blk = idx >> 1, half = idx & 1;
        gload_lds16(A + (size_t)(m0 + blk * 16 + lr) * 512 + k0 + half * 32 + lq * 8,
                    &As[blk * 1024 + half * 512]);
      } else {
        int j = idx - 8, blk = j >> 1, half = j & 1;
        gload_lds16(Bt + (size_t)(n0 + blk * 16 + lr) * 512 + k0 + half * 32 + lq * 8,
                    &Bs[blk * 1024 + half * 512]);
      }
    }
    __syncthreads();
#pragma unroll
    for (int half = 0; half < 2; ++half) {
      bf16x8 af[2], bfr[4];
#pragma unroll
      for (int i = 0; i < 2; ++i)
        af[i] = *(const bf16x8*)&As[(wm * 2 + i) * 1024 + half * 512 + l * 8];
#pragma unroll
      for (int j = 0; j < 4; ++j)
        bfr[j] = *(const bf16x8*)&Bs[(wn * 4 + j) * 1024 + half * 512 + l * 8];
#pragma unroll
      for (int i = 0; i < 2; ++i)
#pragma unroll
        for (int j = 0; j < 4; ++j) acc[i][j] = mfma16(af[i], bfr[j], acc[i][j]);
    }
    __syncthreads();
  }

#pragma unroll
  for (int i = 0; i < 2; ++i)
#pragma unroll
    for (int j = 0; j < 4; ++j) {
      int col = wn * 64 + j * 16 + lr;
      float bv = bias[n0 + col];
#pragma unroll
      for (int r = 0; r < 4; ++r) {
        int row = wm * 32 + i * 16 + lq * 4 + r;
        Cs[row * 132 + col] = acc[i][j][r] + bv;
      }
    }
  __syncthreads();
#pragma unroll
  for (int p = 0; p < 4; ++p) {
    int row = p * 16 + (tid >> 4), c = (tid & 15) * 8;
    float4 v0 = *(const float4*)&Cs[row * 132 + c];
    float4 v1 = *(const float4*)&Cs[row * 132 + c + 4];
    float* op = &outf[(size_t)(m0 + row) * 512 + n0 + c];
    *(float4*)op = v0;
    *(float4*)(op + 4) = v1;
  }
}

// ---------- attention: K staged in LDS (bulk), V reuses buffer, O-tile coalesced ----------
__global__ __launch_bounds__(256)
void k_attn(const ushort_t* __restrict__ qa, const ushort_t* __restrict__ ka,
            const ushort_t* __restrict__ vta, ushort_t* __restrict__ ao) {
  __shared__ __align__(16) ushort_t S[20 * 1024];  // 40960 B: K, then V, then O-tile
  const int tid = threadIdx.x, w = tid >> 6, l = tid & 63;
  const int lr = l & 15, lq = l >> 4;
  const int bh = blockIdx.y, qt0 = blockIdx.x * 64;
  const int qrow = qt0 + w * 16;

  // --- bulk-stage K: 20 blocks of 16 rows, A-frag layout ---
  const ushort_t* kbase = ka + (size_t)bh * 4096 * 64;
#pragma unroll
  for (int i = 0; i < 10; ++i) {
    int idx = w * 10 + i, blk = idx >> 1, half = idx & 1;
    int row = qt0 - 128 + blk * 16 + lr;
    row = min(max(row, 0), 4095);
    gload_lds16(kbase + (size_t)row * 64 + half * 32 + lq * 8, &S[blk * 1024 + half * 512]);
  }

  const ushort_t* qp = qa + ((size_t)bh * 4096 + qrow + lr) * 64 + lq * 8;
  bf16x8 qf0 = *(const bf16x8*)qp;
  bf16x8 qf1 = *(const bf16x8*)(qp + 32);

  __syncthreads();  // K staged

  // --- QK from LDS + fused exp/pack (wave w's tile kt -> K block w+kt) ---
  const float Cc = 0.125f * 1.4426950408889634f;
  uint2 pk[18];
  pk[17].x = 0u; pk[17].y = 0u;
  float ps = 0.f;
#pragma unroll
  for (int kt = 0; kt < 17; ++kt) {
    const ushort_t* kp = &S[(w + kt) * 1024 + l * 8];
    bf16x8 kf0 = *(const bf16x8*)kp;
    bf16x8 kf1 = *(const bf16x8*)(kp + 512);
    floatx4 s = (floatx4)0.0f;
    s = mfma16(kf0, qf0, s);
    s = mfma16(kf1, qf1, s);
    float p[4];
#pragma unroll
    for (int r = 0; r < 4; ++r) {
      int r_rel = kt * 16 + lq * 4 + r;
      int kj = qrow - 128 + r_rel;
      bool ok = (kj >= 0) && (kj < 4096) && (r_rel >= lr) && (r_rel - lr <= 256);
      float e = ok ? exp2f(s[r] * Cc) : 0.f;
      ps += e;
      p[r] = e;
    }
    pk[kt].x = (unsigned)f2bf(p[0]) | ((unsigned)f2bf(p[1]) << 16);
    pk[kt].y = (unsigned)f2bf(p[2]) | ((unsigned)f2bf(p[3]) << 16);
  }

  ps += __shfl_xor(ps, 16, 64);
  ps += __shfl_xor(ps, 32, 64);
  float inv = __builtin_amdgcn_rcpf(ps);
  float invr[4];
#pragma unroll
  for (int r = 0; r < 4; ++r) invr[r] = __shfl(inv, lq * 4 + r, 64);

  __syncthreads();  // all waves done reading K from S

  // --- bulk-stage V into same buffer (B-frag layout, tiles t = kt2*4+nt) ---
  const ushort_t* vbase = vta + (size_t)bh * 64 * 4096;
#pragma unroll
  for (int i = 0; i < 10; ++i) {
    int t = w * 10 + i, kt2 = t >> 2, nt = t & 3;
    int d = nt * 16 + lr;
    int key = qt0 - 128 + kt2 * 32 + lq * 8;
    key = min(max(key, 0), 4088);
    gload_lds16(vbase + (size_t)d * 4096 + key, &S[t * 512]);
  }

  // --- P transform (C-layout -> A-frag) via shfl, into registers (no LDS dep) ---
  const int srcA = ((l >> 4) & 1) * 32 + lr;
  const int srcB = srcA + 16;
  const bool selhi = (l & 32) != 0;
  bf16x8 pu9[9];
#pragma unroll
  for (int kk = 0; kk < 9; ++kk) {
    unsigned e0 = __shfl(pk[2 * kk].x, srcA, 64);
    unsigned e1 = __shfl(pk[2 * kk].y, srcA, 64);
    unsigned e2 = __shfl(pk[2 * kk].x, srcB, 64);
    unsigned e3 = __shfl(pk[2 * kk].y, srcB, 64);
    unsigned o0 = __shfl(pk[2 * kk + 1].x, srcA, 64);
    unsigned o1 = __shfl(pk[2 * kk + 1].y, srcA, 64);
    unsigned o2 = __shfl(pk[2 * kk + 1].x, srcB, 64);
    unsigned o3 = __shfl(pk[2 * kk + 1].y, srcB, 64);
    union { uint4v u; bf16x8 b; } pu;
    pu.u[0] = selhi ? o0 : e0;
    pu.u[1] = selhi ? o1 : e1;
    pu.u[2] = selhi ? o2 : e2;
    pu.u[3] = selhi ? o3 : e3;
    pu9[kk] = pu.b;
  }

  __syncthreads();  // V staged

  // --- PV ---
  floatx4 oacc[4];
#pragma unroll
  for (int nt = 0; nt < 4; ++nt) oacc[nt] = (floatx4)0.0f;
#pragma unroll
  for (int kk = 0; kk < 9; ++kk) {
    int keyrel = w * 16 + kk * 32 + lq * 8;
    keyrel = min(keyrel, 312);
    int kt2 = keyrel >> 5, seg = (keyrel >> 3) & 3;
    const ushort_t* vsp = &S[kt2 * 2048 + seg * 128 + lr * 8];
#pragma unroll
    for (int nt = 0; nt < 4; ++nt) {
      bf16x8 vf = *(const bf16x8*)(vsp + nt * 512);
      oacc[nt] = mfma16(pu9[kk], vf, oacc[nt]);
    }
  }

  __syncthreads();  // all waves done reading V

  // --- O-tile to LDS (64x64, stride 72), then coalesced 16B stores ---
#pragma unroll
  for (int nt = 0; nt < 4; ++nt)
#pragma unroll
    for (int r = 0; r < 4; ++r)
      S[(w * 16 + lq * 4 + r) * 72 + nt * 16 + lr] = f2bf(oacc[nt][r] * invr[r]);
  __syncthreads();

  int b = bh >> 3, h = bh & 7;
#pragma unroll
  for (int p = 0; p < 2; ++p) {
    int row = p * 32 + (tid >> 3), c8 = (tid & 7) * 8;
    ushortx8 vv = *(const ushortx8*)&S[row * 72 + c8];
    *(ushortx8*)&ao[((size_t)(b * 4096 + qt0 + row)) * 512 + h * 64 + c8] = vv;
  }
}

// ---------- launch ----------
extern "C" void kernel_launch(void* const* d_in, const int* in_sizes, int n_in,
                              void* d_out, int out_size, void* d_ws, size_t ws_size,
                              hipStream_t stream) {
  const float* x    = (const float*)d_in[0];
  const float* Wqkv = (const float*)d_in[1];
  const float* Wout = (const float*)d_in[2];
  const float* bout = (const float*)d_in[3];
  float* out = (float*)d_out;
  char* ws = (char*)d_ws;
  const size_t MB = 1024 * 1024;

  ushort_t* xb    = (ushort_t*)(ws);                 // 8 MB (reused as ao after gemm1)
  ushort_t* wqkvT = (ushort_t*)(ws + 8 * MB);        // 1.5 MB
  ushort_t* woutT = (ushort_t*)(ws + 9 * MB + MB/2); // 0.5 MB
  ushort_t* q     = (ushort_t*)(ws + 10 * MB);       // 8 MB
  ushort_t* k     = (ushort_t*)(ws + 18 * MB);       // 8 MB
  ushort_t* vt    = (ushort_t*)(ws + 26 * MB);       // 8 MB  (total 34 MB)
  ushort_t* ao    = xb;

  k_prep<<<5120, 256, 0, stream>>>(x, xb, Wqkv, wqkvT, Wout, woutT);
  k_gemm1<<<dim3(64, 12), 256, 0, stream>>>(xb, wqkvT, q, k, vt);
  k_attn<<<dim3(64, 16), 256, 0, stream>>>(q, k, vt, ao);
  k_gemm2<<<dim3(128, 4), 256, 0, stream>>>(ao, woutT, out, bout);
}